// Round 3
// baseline (2125.268 us; speedup 1.0000x reference)
//
#include <hip/hip_runtime.h>
#include <math.h>

// FNO2D: B=16, H=W=256, C_IN=C_OUT=2, WIDTH=64, MODES=16, NLAYERS=4
// Partial DFTs (only 32 kx rows x 16 ky cols needed), all fp32.
// Batch processed in 2 chunks of CB=8 to keep ws under ~224 MB.
// h kept channels-last [b][hh][w][64], updated in place per (b,hh)-row.

#define CB 8   // batch chunk size

// ---- workspace layout (float offsets), all for one batch chunk ----
static const long long SZ_HC   = (long long)CB*256*256*64;   // 33,554,432 (128 MB)
static const long long OFF_H   = 0;
static const long long SZ_Y1C  = (long long)CB*16*256*64;    // 2,097,152 per plane
static const long long OFF_Y1RE= SZ_HC;
static const long long OFF_Y1IM= OFF_Y1RE + SZ_Y1C;
static const long long OFF_G2  = OFF_Y1RE;                   // union: float2 [b][h][ky][o] = 2*SZ_Y1C floats
static const long long SZ_FTC  = (long long)CB*32*16*64;     // 262,144 per plane
static const long long OFF_FTRE= OFF_Y1RE + 2*SZ_Y1C;
static const long long OFF_FTIM= OFF_FTRE + SZ_FTC;
static const long long OFF_ORE = OFF_FTRE + 2*SZ_FTC;
static const long long OFF_OIM = OFF_FTRE + 3*SZ_FTC;
static const long long SZ_WT   = 4LL*32*16*64*64;            // 8,388,608 per plane (all layers)
static const long long OFF_WTRE= OFF_FTRE + 4*SZ_FTC;
static const long long OFF_WTIM= OFF_WTRE + SZ_WT;
static const long long OFF_CWT = OFF_WTIM + SZ_WT;           // [l][i][o] 16384
static const long long OFF_FW  = OFF_CWT + 4LL*64*64;        // [w][32] (cos,-sin per ky) 8192
static const long long OFF_TW  = OFF_FW + 256LL*32;          // float2[256] (cos,sin)
static const long long WS_FLOATS = OFF_TW + 512;             // 55,599,616 floats ~ 212.1 MB

#define GELU(v) (0.5f*(v)*(1.0f + erff((v)*0.70710678118654752f)))

// ---- tables: master twiddle (cos,sin of 2*pi*k/256) and DFT-W matrix ----
__global__ void k_init_tables(float* ws) {
    int t = threadIdx.x;
    float ang = (float)t * 0.0245436926061702596f; // 2*pi/256
    float s, c;
    sincosf(ang, &s, &c);
    ((float2*)(ws + OFF_TW))[t] = make_float2(c, s);
    float* fw = ws + OFF_FW;
    for (int ky = 0; ky < 16; ky++) {
        float a2 = (float)((ky * t) & 255) * 0.0245436926061702596f;
        float ss, cc;
        sincosf(a2, &ss, &cc);
        fw[t*32 + 2*ky]     = cc;   // Re multiplier
        fw[t*32 + 2*ky + 1] = -ss;  // Im multiplier (e^{-i theta})
    }
}

// ---- weight transpose via LDS tiles: [l][i][o][x][ky] -> [l][kxi][ky][i][o] ----
// block: (l, i, tsel, mh, p); handles a 64(o) x 128(m) sub-slice, m = x*16+ky
__global__ __launch_bounds__(256) void k_wtrans(const float* w1r, const float* w1i,
                                                const float* w2r, const float* w2i,
                                                float* ws) {
    __shared__ float s_t[128*65];
    int t = threadIdx.x;
    int bid = blockIdx.x;                 // 2048 blocks
    int p    = bid & 1;
    int mh   = (bid >> 1) & 1;
    int tsel = (bid >> 2) & 1;
    int i    = (bid >> 3) & 63;
    int l    = bid >> 9;
    const float* src = tsel == 0 ? (p ? w1i : w1r) : (p ? w2i : w2r);
    const float* srcbase = src + ((long long)(l*64 + i)*64)*256;  // [o][256]
    int msub = mh*128;
    for (int j = 0; j < 8; j++) {
        int n = j*256 + t;                // 0..2047
        int o = n >> 5, mf4 = n & 31;
        float4 v = *(const float4*)(srcbase + o*256 + msub + mf4*4);
        int m0 = mf4*4;
        s_t[(m0+0)*65 + o] = v.x;
        s_t[(m0+1)*65 + o] = v.y;
        s_t[(m0+2)*65 + o] = v.z;
        s_t[(m0+3)*65 + o] = v.w;
    }
    __syncthreads();
    float* dst = ws + (p ? OFF_WTIM : OFF_WTRE);
    int o4 = t & 15, mq = t >> 4;
    for (int it = 0; it < 8; it++) {
        int ml = it*16 + mq;
        float4 w = make_float4(s_t[ml*65 + o4*4 + 0], s_t[ml*65 + o4*4 + 1],
                               s_t[ml*65 + o4*4 + 2], s_t[ml*65 + o4*4 + 3]);
        long long idx = ((long long)(l*512 + tsel*256 + msub + ml))*4096 + i*64 + o4*4;
        *(float4*)(dst + idx) = w;
    }
}

// ---- cw transpose: [l][o][i] -> [l][i][o] (tiny) ----
__global__ void k_cwtrans(const float* cw, float* ws) {
    int gid = blockIdx.x * 256 + threadIdx.x;  // 4*64*64
    int o = gid & 63;
    int i = (gid >> 6) & 63;
    int l = gid >> 12;
    ws[OFF_CWT + gid] = cw[(l*64 + o)*64 + i];
}

// ---- lift: h[b,hh,w,c] = x0*lw[0,c] + x1*lw[1,c] + lb[c], chunk-local ----
// one float4 (4 channels) per thread; grid = SZ_HC/1024 blocks
__global__ __launch_bounds__(256) void k_lift(const float* x, const float* lw,
                                              const float* lb, float* ws, int bbase) {
    long long gid4 = (long long)blockIdx.x * 256 + threadIdx.x;  // < SZ_HC/4
    int c4 = (int)(gid4 & 15);
    long long pixl = gid4 >> 4;
    const float* xp = x + ((long long)bbase*65536 + pixl)*2;
    float x0 = xp[0], x1 = xp[1];
    int c = c4*4;
    float4 a  = *(const float4*)&lw[c];
    float4 b  = *(const float4*)&lw[64 + c];
    float4 bb = *(const float4*)&lb[c];
    float4 r;
    r.x = x0*a.x + x1*b.x + bb.x;
    r.y = x0*a.y + x1*b.y + bb.y;
    r.z = x0*a.z + x1*b.z + bb.z;
    r.w = x0*a.w + x1*b.w + bb.w;
    *(float4*)&ws[OFF_H + gid4*4] = r;
}

// ---- DFT along W: Y1[b,ky,h,c] = sum_w h[b,h,w,c] * e^{-2pi i ky w/256} ----
// block = one (b,hh) row (b chunk-local); thread: ky = t&15, c0 = 4*(t>>4)
__global__ __launch_bounds__(256) void k_dftw(float* ws) {
    __shared__ __align__(16) float s_fw[256*32];
    __shared__ __align__(16) float s_h[64*64];
    int t = threadIdx.x;
    int bh = blockIdx.x;                  // [0, CB*256)
    const float* fwg = ws + OFF_FW;
    for (int j = 0; j < 8; j++)
        ((float4*)s_fw)[j*256 + t] = ((const float4*)fwg)[j*256 + t];
    const float* hrow = ws + OFF_H + (long long)bh * (256*64);
    int kq = t & 15;
    int cq = t >> 4;
    float accRe[4] = {0.f,0.f,0.f,0.f}, accIm[4] = {0.f,0.f,0.f,0.f};
    for (int q = 0; q < 4; q++) {
        __syncthreads();
        const float4* src = (const float4*)(hrow + q*64*64);
        for (int j = 0; j < 4; j++)
            ((float4*)s_h)[j*256 + t] = src[j*256 + t];
        __syncthreads();
        for (int wl = 0; wl < 64; wl++) {
            int w = q*64 + wl;
            float2 f = *(const float2*)&s_fw[w*32 + 2*kq];
            float4 hv = *(const float4*)&s_h[wl*64 + 4*cq];
            accRe[0] += f.x*hv.x; accRe[1] += f.x*hv.y; accRe[2] += f.x*hv.z; accRe[3] += f.x*hv.w;
            accIm[0] += f.y*hv.x; accIm[1] += f.y*hv.y; accIm[2] += f.y*hv.z; accIm[3] += f.y*hv.w;
        }
    }
    int b = bh >> 8, hh = bh & 255;
    long long base = ((long long)(b*16 + kq)*256 + hh)*64 + 4*cq;
    *(float4*)&ws[OFF_Y1RE + base] = make_float4(accRe[0], accRe[1], accRe[2], accRe[3]);
    *(float4*)&ws[OFF_Y1IM + base] = make_float4(accIm[0], accIm[1], accIm[2], accIm[3]);
}

// ---- DFT along H: FT[b,kxi,ky,c] = sum_h Y1[b,ky,h,c] * e^{-2pi i kx' h/256} ----
// block = (b, ky, chalf): 256 blocks; thread: kxi = t&31, c = chalf*32 + 4*(t>>5)
__global__ __launch_bounds__(256) void k_dfth(float* ws) {
    __shared__ __align__(16) float s_yre[64*32];
    __shared__ __align__(16) float s_yim[64*32];
    __shared__ __align__(16) float s_tw[512];
    int t = threadIdx.x;
    int bk = blockIdx.x;
    int chalf = bk & 1;
    int ky = (bk >> 1) & 15;
    int b = bk >> 5;
    ((float2*)s_tw)[t] = ((const float2*)(ws + OFF_TW))[t];
    int kxi = t & 31;
    int cq = t >> 5;                      // 0..7
    int kxa = (kxi < 16) ? kxi : (224 + kxi);
    float accRe[4] = {0.f,0.f,0.f,0.f}, accIm[4] = {0.f,0.f,0.f,0.f};
    const float* yre = ws + OFF_Y1RE + (long long)(b*16 + ky)*(256*64);
    const float* yim = ws + OFF_Y1IM + (long long)(b*16 + ky)*(256*64);
    for (int chunk = 0; chunk < 4; chunk++) {
        __syncthreads();
        for (int j = 0; j < 2; j++) {
            int n = j*256 + t;            // 0..511
            int hl = n >> 3, c4 = n & 7;
            long long soff = (long long)(chunk*64 + hl)*64 + chalf*32 + c4*4;
            ((float4*)s_yre)[hl*8 + c4] = *(const float4*)(yre + soff);
            ((float4*)s_yim)[hl*8 + c4] = *(const float4*)(yim + soff);
        }
        __syncthreads();
        for (int hl = 0; hl < 64; hl++) {
            int h = chunk*64 + hl;
            float2 tw = ((const float2*)s_tw)[(kxa*h) & 255];
            float4 yr = *(const float4*)&s_yre[hl*32 + 4*cq];
            float4 yi = *(const float4*)&s_yim[hl*32 + 4*cq];
            // FT += Y * (c - i s)
            accRe[0] += yr.x*tw.x + yi.x*tw.y;
            accRe[1] += yr.y*tw.x + yi.y*tw.y;
            accRe[2] += yr.z*tw.x + yi.z*tw.y;
            accRe[3] += yr.w*tw.x + yi.w*tw.y;
            accIm[0] += yi.x*tw.x - yr.x*tw.y;
            accIm[1] += yi.y*tw.x - yr.y*tw.y;
            accIm[2] += yi.z*tw.x - yr.z*tw.y;
            accIm[3] += yi.w*tw.x - yr.w*tw.y;
        }
    }
    long long base = ((long long)((b*32 + kxi)*16 + ky))*64 + chalf*32 + 4*cq;
    *(float4*)&ws[OFF_FTRE + base] = make_float4(accRe[0], accRe[1], accRe[2], accRe[3]);
    *(float4*)&ws[OFF_FTIM + base] = make_float4(accIm[0], accIm[1], accIm[2], accIm[3]);
}

// ---- mode mix: O[b,kxi,ky,o] = sum_i FT[b,kxi,ky,i] * W[l,kxi,ky,i,o] (complex) ----
// block = (kxi,ky): 512 blocks; thread: o = t&63, 2 b's per thread
__global__ __launch_bounds__(256) void k_mix(float* ws, int l) {
    __shared__ __align__(16) float2 s_ft[CB*64];
    int t = threadIdx.x;
    int kk = blockIdx.x;
    int kxi = kk >> 4, ky = kk & 15;
    for (int j = 0; j < 2; j++) {
        int idx = j*256 + t;              // 0..511
        int i = idx & 63, b = idx >> 6;   // b 0..7
        long long a = ((long long)(b*32 + kxi)*16 + ky)*64 + i;
        s_ft[b*64 + i] = make_float2(ws[OFF_FTRE + a], ws[OFF_FTIM + a]);
    }
    __syncthreads();
    int o = t & 63, bq = t >> 6;          // bq 0..3, 2 b's each
    const float* wr = ws + OFF_WTRE + (((long long)l*32 + kxi)*16 + ky)*4096;
    const float* wi = ws + OFF_WTIM + (((long long)l*32 + kxi)*16 + ky)*4096;
    float accRe[2] = {0.f,0.f}, accIm[2] = {0.f,0.f};
    #pragma unroll 4
    for (int i = 0; i < 64; i++) {
        float wrv = wr[i*64 + o], wiv = wi[i*64 + o];
        #pragma unroll
        for (int j = 0; j < 2; j++) {
            float2 a = s_ft[(bq*2 + j)*64 + i];
            accRe[j] += a.x*wrv - a.y*wiv;
            accIm[j] += a.x*wiv + a.y*wrv;
        }
    }
    #pragma unroll
    for (int j = 0; j < 2; j++) {
        int b = bq*2 + j;
        long long a = ((long long)(b*32 + kxi)*16 + ky)*64 + o;
        ws[OFF_ORE + a] = accRe[j];
        ws[OFF_OIM + a] = accIm[j];
    }
}

// ---- IDFT along H: g[b,h,ky,o] = scale * sum_kxi O * e^{+2pi i kx' h/256} ----
// block = (b, ky, hh2): 256 blocks, 128 h each; thread: o = t&63, 32 h's
__global__ __launch_bounds__(256) void k_idfth(float* ws) {
    __shared__ __align__(16) float2 s_o[32*64];
    __shared__ __align__(16) float s_tw[512];
    int t = threadIdx.x;
    int bk = blockIdx.x;
    int hh2 = bk & 1;
    int ky = (bk >> 1) & 15;
    int b = bk >> 5;
    ((float2*)s_tw)[t] = ((const float2*)(ws + OFF_TW))[t];
    for (int j = 0; j < 8; j++) {
        int idx = j*256 + t;
        int o = idx & 63, kxi = idx >> 6;
        long long a = ((long long)(b*32 + kxi)*16 + ky)*64 + o;
        s_o[idx] = make_float2(ws[OFF_ORE + a], ws[OFF_OIM + a]);
    }
    __syncthreads();
    int o = t & 63, hq = t >> 6;
    float orr[32], oii[32];
    #pragma unroll
    for (int k = 0; k < 32; k++) { float2 v = s_o[k*64 + o]; orr[k] = v.x; oii[k] = v.y; }
    float scale = (ky == 0 ? 1.0f : 2.0f) * (1.0f/65536.0f);
    float2* g2 = (float2*)(ws + OFF_G2);
    for (int j = 0; j < 32; j++) {
        int h = hh2*128 + j*4 + hq;
        float gr = 0.f, gi = 0.f;
        #pragma unroll
        for (int k = 0; k < 32; k++) {
            int kxa = (k < 16) ? k : (224 + k);
            float2 tw = ((const float2*)s_tw)[(kxa*h) & 255];
            gr += orr[k]*tw.x - oii[k]*tw.y;
            gi += orr[k]*tw.y + oii[k]*tw.x;
        }
        long long a = (((long long)b*256 + h)*16 + ky)*64 + o;
        g2[a] = make_float2(gr*scale, gi*scale);
    }
}

// ---- fused: h_new = gelu( IDFT-W(g) + conv1x1(h) + cb ), in place per row ----
// block = (b,hh) row (chunk-local); thread tile 4w x 8o; two 128-w halves
__global__ __launch_bounds__(256) void k_layer_out(float* ws, const float* cb, int l) {
    __shared__ __align__(16) float s_h[128*64];    // XOR-swizzled float4 granules
    __shared__ __align__(16) float s_g[16*64*2];   // float2 [ky][o]
    __shared__ __align__(16) float s_cw[64*64];    // [i][o]
    __shared__ __align__(16) float s_tw[512];
    int t = threadIdx.x;
    int bh = blockIdx.x;
    ((float2*)s_tw)[t] = ((const float2*)(ws + OFF_TW))[t];
    {
        const float4* src = (const float4*)(ws + OFF_CWT + (long long)l*4096);
        for (int j = 0; j < 4; j++) ((float4*)s_cw)[j*256 + t] = src[j*256 + t];
        const float4* gsrc = (const float4*)(ws + OFF_G2 + (long long)bh*2048);
        for (int j = 0; j < 2; j++) ((float4*)s_g)[j*256 + t] = gsrc[j*256 + t];
    }
    int to = t & 7, twid = t >> 3;
    int o0 = 8*to;
    float cbv[8];
    #pragma unroll
    for (int k = 0; k < 8; k++) cbv[k] = cb[o0 + k];
    float* hbase = ws + OFF_H + (long long)bh * (256*64);
    for (int half = 0; half < 2; half++) {
        __syncthreads();
        {
            const float4* src = (const float4*)(hbase + half*128*64);
            for (int j = 0; j < 8; j++) {
                int G = j*256 + t;
                int wl = G >> 4, g = G & 15;
                int gs = g ^ ((wl >> 2) & 7);
                ((float4*)s_h)[wl*16 + gs] = src[G];
            }
        }
        __syncthreads();
        float acc[4][8];
        #pragma unroll
        for (int wq = 0; wq < 4; wq++)
            #pragma unroll
            for (int oq = 0; oq < 8; oq++) acc[wq][oq] = cbv[oq];
        // conv1x1: acc += sum_i h[wl][i] * cwT[i][o]
        for (int it = 0; it < 16; it++) {
            float aa[4][4];
            #pragma unroll
            for (int wq = 0; wq < 4; wq++) {
                int wl = 4*twid + wq;
                int gs = it ^ (twid & 7);
                float4 v = ((const float4*)s_h)[wl*16 + gs];
                aa[wq][0] = v.x; aa[wq][1] = v.y; aa[wq][2] = v.z; aa[wq][3] = v.w;
            }
            #pragma unroll
            for (int ii = 0; ii < 4; ii++) {
                float4 b0 = *(const float4*)&s_cw[(4*it + ii)*64 + o0];
                float4 b1 = *(const float4*)&s_cw[(4*it + ii)*64 + o0 + 4];
                float bb[8] = {b0.x,b0.y,b0.z,b0.w,b1.x,b1.y,b1.z,b1.w};
                #pragma unroll
                for (int wq = 0; wq < 4; wq++)
                    #pragma unroll
                    for (int oq = 0; oq < 8; oq++)
                        acc[wq][oq] += aa[wq][ii]*bb[oq];
            }
        }
        // x1: acc += sum_ky (gr*cos - gi*sin); alpha/65536 pre-folded into g
        for (int ky = 0; ky < 16; ky++) {
            float gre[8], gim[8];
            #pragma unroll
            for (int j = 0; j < 4; j++) {
                float4 v = ((const float4*)s_g)[ky*32 + (o0 >> 1) + j];
                gre[2*j] = v.x; gim[2*j] = v.y; gre[2*j+1] = v.z; gim[2*j+1] = v.w;
            }
            #pragma unroll
            for (int wq = 0; wq < 4; wq++) {
                int w = half*128 + 4*twid + wq;
                float2 tw = ((const float2*)s_tw)[(ky*w) & 255];
                #pragma unroll
                for (int oq = 0; oq < 8; oq++)
                    acc[wq][oq] += gre[oq]*tw.x - gim[oq]*tw.y;
            }
        }
        // gelu + in-place store
        #pragma unroll
        for (int wq = 0; wq < 4; wq++) {
            int wl = 4*twid + wq;
            float r[8];
            #pragma unroll
            for (int oq = 0; oq < 8; oq++) { float v = acc[wq][oq]; r[oq] = GELU(v); }
            float* dst = hbase + ((long long)(half*128 + wl))*64 + o0;
            *(float4*)dst       = make_float4(r[0],r[1],r[2],r[3]);
            *(float4*)(dst + 4) = make_float4(r[4],r[5],r[6],r[7]);
        }
    }
}

// ---- projection: out = gelu(h@p1 + b1) @ p2 + b2, per (b,hh) row ----
__global__ __launch_bounds__(256) void k_proj(float* ws, const float* p1w, const float* p1b,
                                              const float* p2w, const float* p2b, float* out) {
    __shared__ __align__(16) float s_h[64*64];
    __shared__ __align__(16) float s_u[32*129];
    __shared__ __align__(16) float s_p2[256];
    int t = threadIdx.x;
    int bh = blockIdx.x;
    if (t < 128) { s_p2[2*t] = p2w[2*t]; s_p2[2*t + 1] = p2w[2*t + 1]; }
    int uq = t & 31, wq = t >> 5;
    int u0 = 4*uq;
    float p1bv[4];
    #pragma unroll
    for (int k = 0; k < 4; k++) p1bv[k] = p1b[u0 + k];
    float p2b0 = p2b[0], p2b1 = p2b[1];
    const float* hbase = ws + OFF_H + (long long)bh * (256*64);
    float* obase = out + (long long)bh * (256*2);
    for (int q = 0; q < 4; q++) {
        __syncthreads();
        const float4* src = (const float4*)(hbase + q*64*64);
        for (int j = 0; j < 4; j++) ((float4*)s_h)[j*256 + t] = src[j*256 + t];
        __syncthreads();
        for (int sub = 0; sub < 2; sub++) {
            float acc[4][4];
            #pragma unroll
            for (int j = 0; j < 4; j++)
                #pragma unroll
                for (int k = 0; k < 4; k++) acc[j][k] = p1bv[k];
            for (int it = 0; it < 16; it++) {
                int i = 4*it;
                float aa[4][4];
                #pragma unroll
                for (int j = 0; j < 4; j++) {
                    float4 v = *(const float4*)&s_h[(sub*32 + 4*wq + j)*64 + i];
                    aa[j][0] = v.x; aa[j][1] = v.y; aa[j][2] = v.z; aa[j][3] = v.w;
                }
                #pragma unroll
                for (int ii = 0; ii < 4; ii++) {
                    float4 pv = *(const float4*)&p1w[(i + ii)*128 + u0];
                    float pp[4] = {pv.x, pv.y, pv.z, pv.w};
                    #pragma unroll
                    for (int j = 0; j < 4; j++)
                        #pragma unroll
                        for (int k = 0; k < 4; k++)
                            acc[j][k] += aa[j][ii]*pp[k];
                }
            }
            #pragma unroll
            for (int j = 0; j < 4; j++) {
                int wl = 4*wq + j;
                #pragma unroll
                for (int k = 0; k < 4; k++) {
                    float v = acc[j][k];
                    s_u[wl*129 + u0 + k] = GELU(v);
                }
            }
            __syncthreads();
            if (t < 128) {
                int wl = t >> 2;
                int co = (t >> 1) & 1, seg = t & 1;
                float s = 0.f;
                #pragma unroll 16
                for (int u = 0; u < 64; u++)
                    s += s_u[wl*129 + seg*64 + u] * s_p2[(seg*64 + u)*2 + co];
                s += __shfl_xor(s, 1);
                if (seg == 0)
                    obase[(q*64 + sub*32 + wl)*2 + co] = s + (co ? p2b1 : p2b0);
            }
            __syncthreads();
        }
    }
}

extern "C" void kernel_launch(void* const* d_in, const int* in_sizes, int n_in,
                              void* d_out, int out_size, void* d_ws, size_t ws_size,
                              hipStream_t stream) {
    (void)in_sizes; (void)n_in; (void)out_size; (void)ws_size;
    const float* x   = (const float*)d_in[0];
    const float* lw  = (const float*)d_in[1];
    const float* lb  = (const float*)d_in[2];
    const float* w1r = (const float*)d_in[3];
    const float* w1i = (const float*)d_in[4];
    const float* w2r = (const float*)d_in[5];
    const float* w2i = (const float*)d_in[6];
    const float* cw  = (const float*)d_in[7];
    const float* cb  = (const float*)d_in[8];
    const float* p1w = (const float*)d_in[9];
    const float* p1b = (const float*)d_in[10];
    const float* p2w = (const float*)d_in[11];
    const float* p2b = (const float*)d_in[12];
    float* ws  = (float*)d_ws;
    float* out = (float*)d_out;

    k_init_tables<<<dim3(1), dim3(256), 0, stream>>>(ws);
    k_wtrans<<<dim3(2048), dim3(256), 0, stream>>>(w1r, w1i, w2r, w2i, ws);
    k_cwtrans<<<dim3(64), dim3(256), 0, stream>>>(cw, ws);
    for (int chunk = 0; chunk < 16/CB; chunk++) {
        k_lift<<<dim3((int)(SZ_HC/1024)), dim3(256), 0, stream>>>(x, lw, lb, ws, chunk*CB);
        for (int l = 0; l < 4; l++) {
            k_dftw<<<dim3(CB*256), dim3(256), 0, stream>>>(ws);
            k_dfth<<<dim3(CB*32), dim3(256), 0, stream>>>(ws);
            k_mix<<<dim3(512), dim3(256), 0, stream>>>(ws, l);
            k_idfth<<<dim3(CB*32), dim3(256), 0, stream>>>(ws);
            k_layer_out<<<dim3(CB*256), dim3(256), 0, stream>>>(ws, cb + l*64, l);
        }
        k_proj<<<dim3(CB*256), dim3(256), 0, stream>>>(ws, p1w, p1b, p2w, p2b,
                                                       out + (long long)chunk*CB*256*256*2);
    }
}

// Round 4
// 1787.534 us; speedup vs baseline: 1.1889x; 1.1889x over previous
//
#include <hip/hip_runtime.h>
#include <math.h>

// FNO2D: B=16, H=W=256, C_IN=C_OUT=2, WIDTH=64, MODES=16, NLAYERS=4
// Partial DFTs (only 32 kx rows x 16 ky cols needed).
// Batch processed in 2 chunks of CB=8. h channels-last [b][hh][w][64].
// This round: k_layer_out rewritten as split-bf16 MFMA GEMM:
//   C[256w x 64o] = [Tw | h][256 x 96] @ [[g],[cw]][96 x 64], + cb, gelu.

#define CB 8   // batch chunk size

typedef __attribute__((ext_vector_type(8))) __bf16 bf16x8;
typedef __attribute__((ext_vector_type(4))) float f32x4;

// ---- workspace layout (float offsets), all for one batch chunk ----
static const long long SZ_HC   = (long long)CB*256*256*64;   // 33,554,432 (128 MB)
static const long long OFF_H   = 0;
static const long long SZ_Y1C  = (long long)CB*16*256*64;    // 2,097,152 per plane
static const long long OFF_Y1RE= SZ_HC;
static const long long OFF_Y1IM= OFF_Y1RE + SZ_Y1C;
static const long long OFF_G2  = OFF_Y1RE;                   // union: float2 [b][h][ky][o]
static const long long SZ_FTC  = (long long)CB*32*16*64;     // 262,144 per plane
static const long long OFF_FTRE= OFF_Y1RE + 2*SZ_Y1C;
static const long long OFF_FTIM= OFF_FTRE + SZ_FTC;
static const long long OFF_ORE = OFF_FTRE + 2*SZ_FTC;
static const long long OFF_OIM = OFF_FTRE + 3*SZ_FTC;
static const long long SZ_WT   = 4LL*32*16*64*64;            // 8,388,608 per plane
static const long long OFF_WTRE= OFF_FTRE + 4*SZ_FTC;
static const long long OFF_WTIM= OFF_WTRE + SZ_WT;
static const long long OFF_CWT = OFF_WTIM + SZ_WT;           // (legacy, unused)
static const long long OFF_FW  = OFF_CWT + 4LL*64*64;        // [w][32] (cos,-sin per ky)
static const long long OFF_TW  = OFF_FW + 256LL*32;          // float2[256] (cos,sin)
static const long long OFF_TWA = OFF_TW + 512;               // twiddle A-frags: 16384 ushort (hi+lo) = 8192 floats
static const long long OFF_CWB = OFF_TWA + 8192;             // cw bf16 hi+lo: 32768 ushort = 16384 floats
static const long long WS_FLOATS = OFF_CWB + 16384;          // ~212.2 MB

#define GELU(v) (0.5f*(v)*(1.0f + erff((v)*0.70710678118654752f)))

// split fp32 into bf16 hi/lo (truncation; |v - hi - lo| <= 2^-14 |v|)
__device__ __forceinline__ void split2(float v, ushort& hi, ushort& lo) {
    unsigned u = __float_as_uint(v);
    hi = (ushort)(u >> 16);
    float fhi = __uint_as_float(u & 0xffff0000u);
    float r = v - fhi;
    lo = (ushort)(__float_as_uint(r) >> 16);
}

union U8 { ushort u[8]; uint4 v; };

// ---- tables: master twiddle, DFT-W matrix, and IDFT-W A-fragments ----
__global__ void k_init_tables(float* ws) {
    int t = threadIdx.x;
    float ang = (float)t * 0.0245436926061702596f; // 2*pi/256
    float s, c;
    sincosf(ang, &s, &c);
    ((float2*)(ws + OFF_TW))[t] = make_float2(c, s);
    float* fw = ws + OFF_FW;
    for (int ky = 0; ky < 16; ky++) {
        float a2 = (float)((ky * t) & 255) * 0.0245436926061702596f;
        float ss, cc;
        sincosf(a2, &ss, &cc);
        fw[t*32 + 2*ky]     = cc;   // Re multiplier
        fw[t*32 + 2*ky + 1] = -ss;  // Im multiplier (e^{-i theta})
    }
    // IDFT-W A-fragments for k_layer_out kstep0: value at (wt, lane, j):
    //   w = wt*16 + (lane&15), kk = 8*(lane>>4)+j, ky = kk>>1
    //   even kk -> cos(2pi ky w/256), odd kk -> -sin(...)
    ushort* twh = (ushort*)(ws + OFF_TWA);
    ushort* twl = twh + 8192;
    int lidx = t & 63;
    int quarter = t >> 6;
    for (int wt = 0; wt < 16; wt++) {
        for (int jq = 0; jq < 2; jq++) {
            int j = quarter*2 + jq;
            int w = wt*16 + (lidx & 15);
            int kk = 8*(lidx >> 4) + j;
            int ky = kk >> 1;
            float a2 = (float)((ky * w) & 255) * 0.0245436926061702596f;
            float ss, cc;
            sincosf(a2, &ss, &cc);
            float val = (kk & 1) ? -ss : cc;
            ushort hi, lo; split2(val, hi, lo);
            twh[(wt*64 + lidx)*8 + j] = hi;
            twl[(wt*64 + lidx)*8 + j] = lo;
        }
    }
}

// ---- weight transpose via LDS tiles: [l][i][o][x][ky] -> [l][kxi][ky][i][o] ----
__global__ __launch_bounds__(256) void k_wtrans(const float* w1r, const float* w1i,
                                                const float* w2r, const float* w2i,
                                                float* ws) {
    __shared__ float s_t[128*65];
    int t = threadIdx.x;
    int bid = blockIdx.x;                 // 2048 blocks
    int p    = bid & 1;
    int mh   = (bid >> 1) & 1;
    int tsel = (bid >> 2) & 1;
    int i    = (bid >> 3) & 63;
    int l    = bid >> 9;
    const float* src = tsel == 0 ? (p ? w1i : w1r) : (p ? w2i : w2r);
    const float* srcbase = src + ((long long)(l*64 + i)*64)*256;  // [o][256]
    int msub = mh*128;
    for (int j = 0; j < 8; j++) {
        int n = j*256 + t;                // 0..2047
        int o = n >> 5, mf4 = n & 31;
        float4 v = *(const float4*)(srcbase + o*256 + msub + mf4*4);
        int m0 = mf4*4;
        s_t[(m0+0)*65 + o] = v.x;
        s_t[(m0+1)*65 + o] = v.y;
        s_t[(m0+2)*65 + o] = v.z;
        s_t[(m0+3)*65 + o] = v.w;
    }
    __syncthreads();
    float* dst = ws + (p ? OFF_WTIM : OFF_WTRE);
    int o4 = t & 15, mq = t >> 4;
    for (int it = 0; it < 8; it++) {
        int ml = it*16 + mq;
        float4 w = make_float4(s_t[ml*65 + o4*4 + 0], s_t[ml*65 + o4*4 + 1],
                               s_t[ml*65 + o4*4 + 2], s_t[ml*65 + o4*4 + 3]);
        long long idx = ((long long)(l*512 + tsel*256 + msub + ml))*4096 + i*64 + o4*4;
        *(float4*)(dst + idx) = w;
    }
}

// ---- cw -> bf16 hi/lo planes: cwb_hi[l][o][i], cwb_lo[l][o][i] ----
__global__ void k_cwtrans(const float* cw, float* ws) {
    int gid = blockIdx.x * 256 + threadIdx.x;  // 16384 = [l][o][i]
    ushort* ch = (ushort*)(ws + OFF_CWB);
    ushort* cl = ch + 16384;
    ushort hi, lo; split2(cw[gid], hi, lo);
    ch[gid] = hi; cl[gid] = lo;
}

// ---- lift: h[b,hh,w,c] = x0*lw[0,c] + x1*lw[1,c] + lb[c], chunk-local ----
__global__ __launch_bounds__(256) void k_lift(const float* x, const float* lw,
                                              const float* lb, float* ws, int bbase) {
    long long gid4 = (long long)blockIdx.x * 256 + threadIdx.x;  // < SZ_HC/4
    int c4 = (int)(gid4 & 15);
    long long pixl = gid4 >> 4;
    const float* xp = x + ((long long)bbase*65536 + pixl)*2;
    float x0 = xp[0], x1 = xp[1];
    int c = c4*4;
    float4 a  = *(const float4*)&lw[c];
    float4 b  = *(const float4*)&lw[64 + c];
    float4 bb = *(const float4*)&lb[c];
    float4 r;
    r.x = x0*a.x + x1*b.x + bb.x;
    r.y = x0*a.y + x1*b.y + bb.y;
    r.z = x0*a.z + x1*b.z + bb.z;
    r.w = x0*a.w + x1*b.w + bb.w;
    *(float4*)&ws[OFF_H + gid4*4] = r;
}

// ---- DFT along W: Y1[b,ky,h,c] = sum_w h[b,h,w,c] * e^{-2pi i ky w/256} ----
__global__ __launch_bounds__(256) void k_dftw(float* ws) {
    __shared__ __align__(16) float s_fw[256*32];
    __shared__ __align__(16) float s_h[64*64];
    int t = threadIdx.x;
    int bh = blockIdx.x;                  // [0, CB*256)
    const float* fwg = ws + OFF_FW;
    for (int j = 0; j < 8; j++)
        ((float4*)s_fw)[j*256 + t] = ((const float4*)fwg)[j*256 + t];
    const float* hrow = ws + OFF_H + (long long)bh * (256*64);
    int kq = t & 15;
    int cq = t >> 4;
    float accRe[4] = {0.f,0.f,0.f,0.f}, accIm[4] = {0.f,0.f,0.f,0.f};
    for (int q = 0; q < 4; q++) {
        __syncthreads();
        const float4* src = (const float4*)(hrow + q*64*64);
        for (int j = 0; j < 4; j++)
            ((float4*)s_h)[j*256 + t] = src[j*256 + t];
        __syncthreads();
        for (int wl = 0; wl < 64; wl++) {
            int w = q*64 + wl;
            float2 f = *(const float2*)&s_fw[w*32 + 2*kq];
            float4 hv = *(const float4*)&s_h[wl*64 + 4*cq];
            accRe[0] += f.x*hv.x; accRe[1] += f.x*hv.y; accRe[2] += f.x*hv.z; accRe[3] += f.x*hv.w;
            accIm[0] += f.y*hv.x; accIm[1] += f.y*hv.y; accIm[2] += f.y*hv.z; accIm[3] += f.y*hv.w;
        }
    }
    int b = bh >> 8, hh = bh & 255;
    long long base = ((long long)(b*16 + kq)*256 + hh)*64 + 4*cq;
    *(float4*)&ws[OFF_Y1RE + base] = make_float4(accRe[0], accRe[1], accRe[2], accRe[3]);
    *(float4*)&ws[OFF_Y1IM + base] = make_float4(accIm[0], accIm[1], accIm[2], accIm[3]);
}

// ---- DFT along H ----
__global__ __launch_bounds__(256) void k_dfth(float* ws) {
    __shared__ __align__(16) float s_yre[64*32];
    __shared__ __align__(16) float s_yim[64*32];
    __shared__ __align__(16) float s_tw[512];
    int t = threadIdx.x;
    int bk = blockIdx.x;
    int chalf = bk & 1;
    int ky = (bk >> 1) & 15;
    int b = bk >> 5;
    ((float2*)s_tw)[t] = ((const float2*)(ws + OFF_TW))[t];
    int kxi = t & 31;
    int cq = t >> 5;                      // 0..7
    int kxa = (kxi < 16) ? kxi : (224 + kxi);
    float accRe[4] = {0.f,0.f,0.f,0.f}, accIm[4] = {0.f,0.f,0.f,0.f};
    const float* yre = ws + OFF_Y1RE + (long long)(b*16 + ky)*(256*64);
    const float* yim = ws + OFF_Y1IM + (long long)(b*16 + ky)*(256*64);
    for (int chunk = 0; chunk < 4; chunk++) {
        __syncthreads();
        for (int j = 0; j < 2; j++) {
            int n = j*256 + t;            // 0..511
            int hl = n >> 3, c4 = n & 7;
            long long soff = (long long)(chunk*64 + hl)*64 + chalf*32 + c4*4;
            ((float4*)s_yre)[hl*8 + c4] = *(const float4*)(yre + soff);
            ((float4*)s_yim)[hl*8 + c4] = *(const float4*)(yim + soff);
        }
        __syncthreads();
        for (int hl = 0; hl < 64; hl++) {
            int h = chunk*64 + hl;
            float2 tw = ((const float2*)s_tw)[(kxa*h) & 255];
            float4 yr = *(const float4*)&s_yre[hl*32 + 4*cq];
            float4 yi = *(const float4*)&s_yim[hl*32 + 4*cq];
            accRe[0] += yr.x*tw.x + yi.x*tw.y;
            accRe[1] += yr.y*tw.x + yi.y*tw.y;
            accRe[2] += yr.z*tw.x + yi.z*tw.y;
            accRe[3] += yr.w*tw.x + yi.w*tw.y;
            accIm[0] += yi.x*tw.x - yr.x*tw.y;
            accIm[1] += yi.y*tw.x - yr.y*tw.y;
            accIm[2] += yi.z*tw.x - yr.z*tw.y;
            accIm[3] += yi.w*tw.x - yr.w*tw.y;
        }
    }
    long long base = ((long long)((b*32 + kxi)*16 + ky))*64 + chalf*32 + 4*cq;
    *(float4*)&ws[OFF_FTRE + base] = make_float4(accRe[0], accRe[1], accRe[2], accRe[3]);
    *(float4*)&ws[OFF_FTIM + base] = make_float4(accIm[0], accIm[1], accIm[2], accIm[3]);
}

// ---- mode mix ----
__global__ __launch_bounds__(256) void k_mix(float* ws, int l) {
    __shared__ __align__(16) float2 s_ft[CB*64];
    int t = threadIdx.x;
    int kk = blockIdx.x;
    int kxi = kk >> 4, ky = kk & 15;
    for (int j = 0; j < 2; j++) {
        int idx = j*256 + t;              // 0..511
        int i = idx & 63, b = idx >> 6;   // b 0..7
        long long a = ((long long)(b*32 + kxi)*16 + ky)*64 + i;
        s_ft[b*64 + i] = make_float2(ws[OFF_FTRE + a], ws[OFF_FTIM + a]);
    }
    __syncthreads();
    int o = t & 63, bq = t >> 6;          // bq 0..3, 2 b's each
    const float* wr = ws + OFF_WTRE + (((long long)l*32 + kxi)*16 + ky)*4096;
    const float* wi = ws + OFF_WTIM + (((long long)l*32 + kxi)*16 + ky)*4096;
    float accRe[2] = {0.f,0.f}, accIm[2] = {0.f,0.f};
    #pragma unroll 4
    for (int i = 0; i < 64; i++) {
        float wrv = wr[i*64 + o], wiv = wi[i*64 + o];
        #pragma unroll
        for (int j = 0; j < 2; j++) {
            float2 a = s_ft[(bq*2 + j)*64 + i];
            accRe[j] += a.x*wrv - a.y*wiv;
            accIm[j] += a.x*wiv + a.y*wrv;
        }
    }
    #pragma unroll
    for (int j = 0; j < 2; j++) {
        int b = bq*2 + j;
        long long a = ((long long)(b*32 + kxi)*16 + ky)*64 + o;
        ws[OFF_ORE + a] = accRe[j];
        ws[OFF_OIM + a] = accIm[j];
    }
}

// ---- IDFT along H: g[b,h,ky,o] (alpha/65536 folded) ----
__global__ __launch_bounds__(256) void k_idfth(float* ws) {
    __shared__ __align__(16) float2 s_o[32*64];
    __shared__ __align__(16) float s_tw[512];
    int t = threadIdx.x;
    int bk = blockIdx.x;
    int hh2 = bk & 1;
    int ky = (bk >> 1) & 15;
    int b = bk >> 5;
    ((float2*)s_tw)[t] = ((const float2*)(ws + OFF_TW))[t];
    for (int j = 0; j < 8; j++) {
        int idx = j*256 + t;
        int o = idx & 63, kxi = idx >> 6;
        long long a = ((long long)(b*32 + kxi)*16 + ky)*64 + o;
        s_o[idx] = make_float2(ws[OFF_ORE + a], ws[OFF_OIM + a]);
    }
    __syncthreads();
    int o = t & 63, hq = t >> 6;
    float orr[32], oii[32];
    #pragma unroll
    for (int k = 0; k < 32; k++) { float2 v = s_o[k*64 + o]; orr[k] = v.x; oii[k] = v.y; }
    float scale = (ky == 0 ? 1.0f : 2.0f) * (1.0f/65536.0f);
    float2* g2 = (float2*)(ws + OFF_G2);
    for (int j = 0; j < 32; j++) {
        int h = hh2*128 + j*4 + hq;
        float gr = 0.f, gi = 0.f;
        #pragma unroll
        for (int k = 0; k < 32; k++) {
            int kxa = (k < 16) ? k : (224 + k);
            float2 tw = ((const float2*)s_tw)[(kxa*h) & 255];
            gr += orr[k]*tw.x - oii[k]*tw.y;
            gi += orr[k]*tw.y + oii[k]*tw.x;
        }
        long long a = (((long long)b*256 + h)*16 + ky)*64 + o;
        g2[a] = make_float2(gr*scale, gi*scale);
    }
}

// ---- fused layer output via MFMA split-bf16:
// C[256w x 64o] = A[256 x 96] @ B[96 x 64];  A = [Tw(k=0..31) | h(k=32..95)],
// B = [[g (2ky interleaved Re/Im)], [cw]];  then + cb, gelu, store h in place.
// block = (b,hh) row; 256 threads = 4 waves, wave -> o-tile, 8 w-tiles/half.
__global__ __launch_bounds__(256) void k_layer_out(float* ws, const float* cb, int l) {
    __shared__ ushort sAhi[128*64];       // [row][64 i] bf16, XOR-swizzled (granule 8)
    __shared__ ushort sAlo[128*64];
    __shared__ ushort sBhi[64*104];       // [o][k] bf16, rows padded to 104
    __shared__ ushort sBlo[64*104];
    int t = threadIdx.x;
    int bh = blockIdx.x;
    int lane = t & 63, wid = t >> 6;
    int oc = lane & 15, g = lane >> 4;

    // ---- fill B: G part (k=0..31) ----
    const float2* g2 = (const float2*)(ws + OFF_G2) + (long long)bh*1024;
    for (int n = t; n < 1024; n += 256) {
        int ky = n >> 6, o = n & 63;
        float2 gv = g2[n];
        ushort h0,l0,h1,l1; split2(gv.x,h0,l0); split2(gv.y,h1,l1);
        int idx = o*104 + 2*ky;
        sBhi[idx] = h0; sBhi[idx+1] = h1;
        sBlo[idx] = l0; sBlo[idx+1] = l1;
    }
    // ---- fill B: CW part (k=32..95) ----
    {
        const ushort* ch = (const ushort*)(ws + OFF_CWB) + (long long)l*4096;
        const ushort* clo = (const ushort*)(ws + OFF_CWB) + 16384 + (long long)l*4096;
        for (int n = t; n < 512; n += 256) {
            int o = n >> 3, i0 = (n & 7)*8;
            *(uint4*)&sBhi[o*104 + 32 + i0] = *(const uint4*)&ch[o*64 + i0];
            *(uint4*)&sBlo[o*104 + 32 + i0] = *(const uint4*)&clo[o*64 + i0];
        }
    }
    __syncthreads();
    // ---- B fragments (held in regs for whole block) ----
    int o = wid*16 + oc;
    bf16x8 B_h[3], B_l[3];
    #pragma unroll
    for (int s = 0; s < 3; s++) {
        int kb = 32*s + 8*g;
        B_h[s] = *(bf16x8*)&sBhi[o*104 + kb];
        B_l[s] = *(bf16x8*)&sBlo[o*104 + kb];
    }
    float cbv = cb[o];
    const ushort* twh = (const ushort*)(ws + OFF_TWA);
    const ushort* twl = twh + 8192;
    float* hrow = ws + OFF_H + (long long)bh*16384;

    for (int half = 0; half < 2; half++) {
        // ---- stage A: h fp32 -> bf16 hi/lo, swizzled ----
        const float* src = hrow + half*8192;
        for (int n = t; n < 1024; n += 256) {
            int row = n >> 3, i0 = (n & 7)*8;
            float4 v0 = *(const float4*)(src + row*64 + i0);
            float4 v1 = *(const float4*)(src + row*64 + i0 + 4);
            U8 hi, lo;
            split2(v0.x,hi.u[0],lo.u[0]); split2(v0.y,hi.u[1],lo.u[1]);
            split2(v0.z,hi.u[2],lo.u[2]); split2(v0.w,hi.u[3],lo.u[3]);
            split2(v1.x,hi.u[4],lo.u[4]); split2(v1.y,hi.u[5],lo.u[5]);
            split2(v1.z,hi.u[6],lo.u[6]); split2(v1.w,hi.u[7],lo.u[7]);
            int idx = row*64 + (i0 ^ ((row & 7) << 3));
            *(uint4*)&sAhi[idx] = hi.v;
            *(uint4*)&sAlo[idx] = lo.v;
        }
        __syncthreads();
        f32x4 acc[8];
        #pragma unroll
        for (int wt = 0; wt < 8; wt++) acc[wt] = (f32x4){0.f,0.f,0.f,0.f};
        #pragma unroll
        for (int wt = 0; wt < 8; wt++) {
            int gwt = half*8 + wt;
            bf16x8 A0h = *(const bf16x8*)&twh[(gwt*64 + lane)*8];
            bf16x8 A0l = *(const bf16x8*)&twl[(gwt*64 + lane)*8];
            int row = wt*16 + oc;
            int base = row*64;
            int sw = (row & 7) << 3;
            bf16x8 A1h = *(bf16x8*)&sAhi[base + ((8*g) ^ sw)];
            bf16x8 A1l = *(bf16x8*)&sAlo[base + ((8*g) ^ sw)];
            bf16x8 A2h = *(bf16x8*)&sAhi[base + ((32 + 8*g) ^ sw)];
            bf16x8 A2l = *(bf16x8*)&sAlo[base + ((32 + 8*g) ^ sw)];
            f32x4 a = acc[wt];
            a = __builtin_amdgcn_mfma_f32_16x16x32_bf16(A0h, B_h[0], a, 0,0,0);
            a = __builtin_amdgcn_mfma_f32_16x16x32_bf16(A0l, B_h[0], a, 0,0,0);
            a = __builtin_amdgcn_mfma_f32_16x16x32_bf16(A0h, B_l[0], a, 0,0,0);
            a = __builtin_amdgcn_mfma_f32_16x16x32_bf16(A1h, B_h[1], a, 0,0,0);
            a = __builtin_amdgcn_mfma_f32_16x16x32_bf16(A1l, B_h[1], a, 0,0,0);
            a = __builtin_amdgcn_mfma_f32_16x16x32_bf16(A1h, B_l[1], a, 0,0,0);
            a = __builtin_amdgcn_mfma_f32_16x16x32_bf16(A2h, B_h[2], a, 0,0,0);
            a = __builtin_amdgcn_mfma_f32_16x16x32_bf16(A2l, B_h[2], a, 0,0,0);
            a = __builtin_amdgcn_mfma_f32_16x16x32_bf16(A2h, B_l[2], a, 0,0,0);
            acc[wt] = a;
        }
        // ---- epilogue: + cb, gelu, in-place store ----
        #pragma unroll
        for (int wt = 0; wt < 8; wt++) {
            int w0 = half*128 + wt*16 + 4*g;
            #pragma unroll
            for (int r = 0; r < 4; r++) {
                float v = acc[wt][r] + cbv;
                hrow[(w0 + r)*64 + o] = GELU(v);
            }
        }
        __syncthreads();
    }
}

// ---- projection: out = gelu(h@p1 + b1) @ p2 + b2, per (b,hh) row ----
__global__ __launch_bounds__(256) void k_proj(float* ws, const float* p1w, const float* p1b,
                                              const float* p2w, const float* p2b, float* out) {
    __shared__ __align__(16) float s_h[64*64];
    __shared__ __align__(16) float s_u[32*129];
    __shared__ __align__(16) float s_p2[256];
    int t = threadIdx.x;
    int bh = blockIdx.x;
    if (t < 128) { s_p2[2*t] = p2w[2*t]; s_p2[2*t + 1] = p2w[2*t + 1]; }
    int uq = t & 31, wq = t >> 5;
    int u0 = 4*uq;
    float p1bv[4];
    #pragma unroll
    for (int k = 0; k < 4; k++) p1bv[k] = p1b[u0 + k];
    float p2b0 = p2b[0], p2b1 = p2b[1];
    const float* hbase = ws + OFF_H + (long long)bh * (256*64);
    float* obase = out + (long long)bh * (256*2);
    for (int q = 0; q < 4; q++) {
        __syncthreads();
        const float4* src = (const float4*)(hbase + q*64*64);
        for (int j = 0; j < 4; j++) ((float4*)s_h)[j*256 + t] = src[j*256 + t];
        __syncthreads();
        for (int sub = 0; sub < 2; sub++) {
            float acc[4][4];
            #pragma unroll
            for (int j = 0; j < 4; j++)
                #pragma unroll
                for (int k = 0; k < 4; k++) acc[j][k] = p1bv[k];
            for (int it = 0; it < 16; it++) {
                int i = 4*it;
                float aa[4][4];
                #pragma unroll
                for (int j = 0; j < 4; j++) {
                    float4 v = *(const float4*)&s_h[(sub*32 + 4*wq + j)*64 + i];
                    aa[j][0] = v.x; aa[j][1] = v.y; aa[j][2] = v.z; aa[j][3] = v.w;
                }
                #pragma unroll
                for (int ii = 0; ii < 4; ii++) {
                    float4 pv = *(const float4*)&p1w[(i + ii)*128 + u0];
                    float pp[4] = {pv.x, pv.y, pv.z, pv.w};
                    #pragma unroll
                    for (int j = 0; j < 4; j++)
                        #pragma unroll
                        for (int k = 0; k < 4; k++)
                            acc[j][k] += aa[j][ii]*pp[k];
                }
            }
            #pragma unroll
            for (int j = 0; j < 4; j++) {
                int wl = 4*wq + j;
                #pragma unroll
                for (int k = 0; k < 4; k++) {
                    float v = acc[j][k];
                    s_u[wl*129 + u0 + k] = GELU(v);
                }
            }
            __syncthreads();
            if (t < 128) {
                int wl = t >> 2;
                int co = (t >> 1) & 1, seg = t & 1;
                float s = 0.f;
                #pragma unroll 16
                for (int u = 0; u < 64; u++)
                    s += s_u[wl*129 + seg*64 + u] * s_p2[(seg*64 + u)*2 + co];
                s += __shfl_xor(s, 1);
                if (seg == 0)
                    obase[(q*64 + sub*32 + wl)*2 + co] = s + (co ? p2b1 : p2b0);
            }
            __syncthreads();
        }
    }
}

extern "C" void kernel_launch(void* const* d_in, const int* in_sizes, int n_in,
                              void* d_out, int out_size, void* d_ws, size_t ws_size,
                              hipStream_t stream) {
    (void)in_sizes; (void)n_in; (void)out_size; (void)ws_size;
    const float* x   = (const float*)d_in[0];
    const float* lw  = (const float*)d_in[1];
    const float* lb  = (const float*)d_in[2];
    const float* w1r = (const float*)d_in[3];
    const float* w1i = (const float*)d_in[4];
    const float* w2r = (const float*)d_in[5];
    const float* w2i = (const float*)d_in[6];
    const float* cw  = (const float*)d_in[7];
    const float* cb  = (const float*)d_in[8];
    const float* p1w = (const float*)d_in[9];
    const float* p1b = (const float*)d_in[10];
    const float* p2w = (const float*)d_in[11];
    const float* p2b = (const float*)d_in[12];
    float* ws  = (float*)d_ws;
    float* out = (float*)d_out;

    k_init_tables<<<dim3(1), dim3(256), 0, stream>>>(ws);
    k_wtrans<<<dim3(2048), dim3(256), 0, stream>>>(w1r, w1i, w2r, w2i, ws);
    k_cwtrans<<<dim3(64), dim3(256), 0, stream>>>(cw, ws);
    for (int chunk = 0; chunk < 16/CB; chunk++) {
        k_lift<<<dim3((int)(SZ_HC/1024)), dim3(256), 0, stream>>>(x, lw, lb, ws, chunk*CB);
        for (int l = 0; l < 4; l++) {
            k_dftw<<<dim3(CB*256), dim3(256), 0, stream>>>(ws);
            k_dfth<<<dim3(CB*32), dim3(256), 0, stream>>>(ws);
            k_mix<<<dim3(512), dim3(256), 0, stream>>>(ws, l);
            k_idfth<<<dim3(CB*32), dim3(256), 0, stream>>>(ws);
            k_layer_out<<<dim3(CB*256), dim3(256), 0, stream>>>(ws, cb + l*64, l);
        }
        k_proj<<<dim3(CB*256), dim3(256), 0, stream>>>(ws, p1w, p1b, p2w, p2b,
                                                       out + (long long)chunk*CB*256*256*2);
    }
}

// Round 5
// 1425.324 us; speedup vs baseline: 1.4911x; 1.2541x over previous
//
#include <hip/hip_runtime.h>
#include <math.h>

// FNO2D: B=16, H=W=256, C_IN=C_OUT=2, WIDTH=64, MODES=16, NLAYERS=4
// Partial DFTs (32 kx rows x 16 ky cols). Batch in 2 chunks of CB=8.
// h stored as TWO bf16 planes (hi+lo, exact split of fp32): h_hi/h_lo
// [b][hh][w][64] ushort. All big GEMMs (dftw, layer_out, proj) use
// split-bf16 MFMA (AhBh + AlBh + AhBl, per-product err ~2^-16).

#define CB 8   // batch chunk size

typedef __attribute__((ext_vector_type(8))) __bf16 bf16x8;
typedef __attribute__((ext_vector_type(4))) float f32x4;

// ---- workspace layout (float offsets), per batch chunk ----
static const long long SZ_HC    = (long long)CB*256*256*64;  // 33,554,432 floats region
static const long long OFF_HLO_F= SZ_HC/2;                   // hi plane: ws[0..), lo plane: ws[OFF_HLO_F..) as ushort
static const long long SZ_Y1C   = (long long)CB*16*256*64;   // 2,097,152 per plane
static const long long OFF_Y1RE = SZ_HC;
static const long long OFF_Y1IM = OFF_Y1RE + SZ_Y1C;
static const long long OFF_G2   = OFF_Y1RE;                  // union: float2 [b][h][ky][o]
static const long long SZ_FTC   = (long long)CB*32*16*64;    // 262,144 per plane
static const long long OFF_FTRE = OFF_Y1RE + 2*SZ_Y1C;
static const long long OFF_FTIM = OFF_FTRE + SZ_FTC;
static const long long OFF_ORE  = OFF_FTRE + 2*SZ_FTC;
static const long long OFF_OIM  = OFF_FTRE + 3*SZ_FTC;
static const long long SZ_WT    = 4LL*32*16*64*64;           // 8,388,608 per plane
static const long long OFF_WTRE = OFF_FTRE + 4*SZ_FTC;
static const long long OFF_WTIM = OFF_WTRE + SZ_WT;
static const long long OFF_CWT  = OFF_WTIM + SZ_WT;          // legacy slot
static const long long OFF_FW   = OFF_CWT + 4LL*64*64;       // legacy slot
static const long long OFF_TW   = OFF_FW + 256LL*32;         // float2[256] (cos,sin)
static const long long OFF_TWA  = OFF_TW + 512;              // layer_out IDFT-W A frags (hi+lo, 16384 ushort)
static const long long OFF_CWB  = OFF_TWA + 8192;            // cw bf16 hi+lo (32768 ushort)
static const long long OFF_FWA  = OFF_CWB + 16384;           // dftw F A-frags hi+lo (16384 ushort)
static const long long OFF_P1T  = OFF_FWA + 8192;            // p1^T bf16 hi+lo (16384 ushort)
static const long long WS_FLOATS= OFF_P1T + 8192;

#define C2PI 0.0245436926061702596f
#define GELU(v) (0.5f*(v)*(1.0f + erff((v)*0.70710678118654752f)))

__device__ __forceinline__ void split2(float v, ushort& hi, ushort& lo) {
    unsigned u = __float_as_uint(v);
    hi = (ushort)(u >> 16);
    float fhi = __uint_as_float(u & 0xffff0000u);
    float r = v - fhi;
    lo = (ushort)(__float_as_uint(r) >> 16);
}

union U8 { ushort u[8]; uint4 v; };

// ---- tables: TW, layer_out A-frags (TWA), dftw A-frags (FWA) ----
__global__ void k_init_tables(float* ws) {
    int t = threadIdx.x;
    float ang = (float)t * C2PI;
    float s, c;
    sincosf(ang, &s, &c);
    ((float2*)(ws + OFF_TW))[t] = make_float2(c, s);
    // TWA: layer_out A (rows w, K=kk): w = wt*16+(lane&15), kk = 8*(lane>>4)+j
    ushort* twh = (ushort*)(ws + OFF_TWA);
    ushort* twl = twh + 8192;
    int lidx = t & 63;
    int quarter = t >> 6;
    for (int wt = 0; wt < 16; wt++) {
        for (int jq = 0; jq < 2; jq++) {
            int j = quarter*2 + jq;
            int w = wt*16 + (lidx & 15);
            int kk = 8*(lidx >> 4) + j;
            int ky = kk >> 1;
            float a2 = (float)((ky * w) & 255) * C2PI;
            float ss, cc; sincosf(a2, &ss, &cc);
            float val = (kk & 1) ? -ss : cc;
            ushort hi, lo; split2(val, hi, lo);
            twh[(wt*64 + lidx)*8 + j] = hi;
            twl[(wt*64 + lidx)*8 + j] = lo;
        }
    }
    // FWA: dftw A (rows kk, K=w): kk = mt*16+(lane&15), w = ks*32+8*(lane>>4)+j
    ushort* fh = (ushort*)(ws + OFF_FWA);
    ushort* fl = fh + 8192;
    for (int n = t; n < 8192; n += 256) {
        int j = n & 7, ln = (n >> 3) & 63, ks = (n >> 9) & 7, mt2 = n >> 12;
        int kk = mt2*16 + (ln & 15);
        int w = ks*32 + 8*(ln >> 4) + j;
        int ky = kk >> 1;
        float a2 = (float)((ky * w) & 255) * C2PI;
        float ss, cc; sincosf(a2, &ss, &cc);
        float val = (kk & 1) ? -ss : cc;
        ushort hi, lo; split2(val, hi, lo);
        fh[n] = hi; fl[n] = lo;
    }
}

// ---- weight transpose: [l][i][o][x][ky] -> [l][kxi][ky][i][o] ----
__global__ __launch_bounds__(256) void k_wtrans(const float* w1r, const float* w1i,
                                                const float* w2r, const float* w2i,
                                                float* ws) {
    __shared__ float s_t[128*65];
    int t = threadIdx.x;
    int bid = blockIdx.x;                 // 2048 blocks
    int p    = bid & 1;
    int mh   = (bid >> 1) & 1;
    int tsel = (bid >> 2) & 1;
    int i    = (bid >> 3) & 63;
    int l    = bid >> 9;
    const float* src = tsel == 0 ? (p ? w1i : w1r) : (p ? w2i : w2r);
    const float* srcbase = src + ((long long)(l*64 + i)*64)*256;
    int msub = mh*128;
    for (int j = 0; j < 8; j++) {
        int n = j*256 + t;
        int o = n >> 5, mf4 = n & 31;
        float4 v = *(const float4*)(srcbase + o*256 + msub + mf4*4);
        int m0 = mf4*4;
        s_t[(m0+0)*65 + o] = v.x;
        s_t[(m0+1)*65 + o] = v.y;
        s_t[(m0+2)*65 + o] = v.z;
        s_t[(m0+3)*65 + o] = v.w;
    }
    __syncthreads();
    float* dst = ws + (p ? OFF_WTIM : OFF_WTRE);
    int o4 = t & 15, mq = t >> 4;
    for (int it = 0; it < 8; it++) {
        int ml = it*16 + mq;
        float4 w = make_float4(s_t[ml*65 + o4*4 + 0], s_t[ml*65 + o4*4 + 1],
                               s_t[ml*65 + o4*4 + 2], s_t[ml*65 + o4*4 + 3]);
        long long idx = ((long long)(l*512 + tsel*256 + msub + ml))*4096 + i*64 + o4*4;
        *(float4*)(dst + idx) = w;
    }
}

// ---- cw -> bf16 hi/lo planes [l][o][i] ----
__global__ void k_cwtrans(const float* cw, float* ws) {
    int gid = blockIdx.x * 256 + threadIdx.x;  // 16384
    ushort* ch = (ushort*)(ws + OFF_CWB);
    ushort* cl = ch + 16384;
    ushort hi, lo; split2(cw[gid], hi, lo);
    ch[gid] = hi; cl[gid] = lo;
}

// ---- p1 transpose -> bf16 hi/lo planes p1t[u(128)][i(64)] ----
__global__ void k_p1trans(const float* p1w, float* ws) {
    int gid = blockIdx.x * 256 + threadIdx.x;  // 8192
    int u = gid >> 6, i = gid & 63;
    ushort* ph = (ushort*)(ws + OFF_P1T);
    ushort hi, lo; split2(p1w[i*128 + u], hi, lo);
    ph[gid] = hi; ph[8192 + gid] = lo;
}

// ---- lift: h = x@lw + lb, split to hi/lo planes ----
__global__ __launch_bounds__(256) void k_lift(const float* x, const float* lw,
                                              const float* lb, float* ws, int bbase) {
    long long gid8 = (long long)blockIdx.x * 256 + threadIdx.x;  // < CB*65536*8
    int c0 = (int)(gid8 & 7) * 8;
    long long pixl = gid8 >> 3;
    const float* xp = x + ((long long)bbase*65536 + pixl)*2;
    float x0 = xp[0], x1 = xp[1];
    U8 hi, lo;
    #pragma unroll
    for (int j = 0; j < 8; j++) {
        int c = c0 + j;
        float v = x0*lw[c] + x1*lw[64 + c] + lb[c];
        split2(v, hi.u[j], lo.u[j]);
    }
    ushort* hH = (ushort*)ws;
    ushort* hL = (ushort*)(ws + OFF_HLO_F);
    *(uint4*)&hH[pixl*64 + c0] = hi.v;
    *(uint4*)&hL[pixl*64 + c0] = lo.v;
}

// ---- DFT-W via MFMA: Y1[kk(32) x c(64)] = F[32x256] @ h[256x64] per (b,hh) row
// h staged transposed [c][w-half] in LDS (XOR-swizzled), K split over 2 halves.
__global__ __launch_bounds__(256) void k_dftw(float* ws) {
    __shared__ ushort sBhi[64*128];
    __shared__ ushort sBlo[64*128];
    int t = threadIdx.x;
    int bh = blockIdx.x;                  // CB*256
    int lane = t & 63, wid = t >> 6;
    int oc = lane & 15, g = lane >> 4;
    const ushort* hH = (const ushort*)ws;
    const ushort* hL = (const ushort*)(ws + OFF_HLO_F);
    const ushort* fh = (const ushort*)(ws + OFF_FWA);
    const ushort* fl = fh + 8192;
    int mt = wid & 1, nt0 = wid >> 1;     // wave tiles: (mt, nt0) and (mt, nt0+2)
    f32x4 acc0 = {0.f,0.f,0.f,0.f}, acc1 = {0.f,0.f,0.f,0.f};
    long long rowbase = (long long)bh * 16384;
    for (int half = 0; half < 2; half++) {
        __syncthreads();
        for (int r = 0; r < 2; r++) {
            int n = r*256 + t;            // 0..511
            int c0 = (n & 7) * 8;
            int w = (n >> 3) * 2;         // 0..126
            long long gidx = rowbase + (long long)(half*128 + w)*64 + c0;
            U8 a, b2;
            a.v  = *(const uint4*)&hH[gidx];
            b2.v = *(const uint4*)&hH[gidx + 64];
            #pragma unroll
            for (int j = 0; j < 8; j++) {
                int c = c0 + j;
                int key = (((c & 7) ^ ((c >> 3) & 7)) << 3);
                *(uint*)&sBhi[c*128 + (w ^ key)] = (uint)a.u[j] | ((uint)b2.u[j] << 16);
            }
            a.v  = *(const uint4*)&hL[gidx];
            b2.v = *(const uint4*)&hL[gidx + 64];
            #pragma unroll
            for (int j = 0; j < 8; j++) {
                int c = c0 + j;
                int key = (((c & 7) ^ ((c >> 3) & 7)) << 3);
                *(uint*)&sBlo[c*128 + (w ^ key)] = (uint)a.u[j] | ((uint)b2.u[j] << 16);
            }
        }
        __syncthreads();
        #pragma unroll
        for (int ksl = 0; ksl < 4; ksl++) {
            int gks = half*4 + ksl;
            bf16x8 Ah = *(const bf16x8*)&fh[((mt*8 + gks)*64 + lane)*8];
            bf16x8 Al = *(const bf16x8*)&fl[((mt*8 + gks)*64 + lane)*8];
            int wof = ksl*32 + 8*g;
            #pragma unroll
            for (int q = 0; q < 2; q++) {
                int c = (nt0 + q*2)*16 + oc;
                int key = (((c & 7) ^ ((c >> 3) & 7)) << 3);
                bf16x8 Bh = *(const bf16x8*)&sBhi[c*128 + (wof ^ key)];
                bf16x8 Bl = *(const bf16x8*)&sBlo[c*128 + (wof ^ key)];
                f32x4 a = q ? acc1 : acc0;
                a = __builtin_amdgcn_mfma_f32_16x16x32_bf16(Ah, Bh, a, 0,0,0);
                a = __builtin_amdgcn_mfma_f32_16x16x32_bf16(Al, Bh, a, 0,0,0);
                a = __builtin_amdgcn_mfma_f32_16x16x32_bf16(Ah, Bl, a, 0,0,0);
                if (q) acc1 = a; else acc0 = a;
            }
        }
    }
    int b = bh >> 8, hh = bh & 255;
    #pragma unroll
    for (int q = 0; q < 2; q++) {
        f32x4 a = q ? acc1 : acc0;
        int c = (nt0 + q*2)*16 + oc;
        #pragma unroll
        for (int r = 0; r < 4; r++) {
            int kk = mt*16 + 4*g + r;
            int ky = kk >> 1;
            long long addr = ((long long)(b*16 + ky)*256 + hh)*64 + c;
            ws[((kk & 1) ? OFF_Y1IM : OFF_Y1RE) + addr] = a[r];
        }
    }
}

// ---- DFT along H (unchanged, fp32 VALU; small) ----
__global__ __launch_bounds__(256) void k_dfth(float* ws) {
    __shared__ __align__(16) float s_yre[64*32];
    __shared__ __align__(16) float s_yim[64*32];
    __shared__ __align__(16) float s_tw[512];
    int t = threadIdx.x;
    int bk = blockIdx.x;
    int chalf = bk & 1;
    int ky = (bk >> 1) & 15;
    int b = bk >> 5;
    ((float2*)s_tw)[t] = ((const float2*)(ws + OFF_TW))[t];
    int kxi = t & 31;
    int cq = t >> 5;
    int kxa = (kxi < 16) ? kxi : (224 + kxi);
    float accRe[4] = {0.f,0.f,0.f,0.f}, accIm[4] = {0.f,0.f,0.f,0.f};
    const float* yre = ws + OFF_Y1RE + (long long)(b*16 + ky)*(256*64);
    const float* yim = ws + OFF_Y1IM + (long long)(b*16 + ky)*(256*64);
    for (int chunk = 0; chunk < 4; chunk++) {
        __syncthreads();
        for (int j = 0; j < 2; j++) {
            int n = j*256 + t;
            int hl = n >> 3, c4 = n & 7;
            long long soff = (long long)(chunk*64 + hl)*64 + chalf*32 + c4*4;
            ((float4*)s_yre)[hl*8 + c4] = *(const float4*)(yre + soff);
            ((float4*)s_yim)[hl*8 + c4] = *(const float4*)(yim + soff);
        }
        __syncthreads();
        for (int hl = 0; hl < 64; hl++) {
            int h = chunk*64 + hl;
            float2 tw = ((const float2*)s_tw)[(kxa*h) & 255];
            float4 yr = *(const float4*)&s_yre[hl*32 + 4*cq];
            float4 yi = *(const float4*)&s_yim[hl*32 + 4*cq];
            accRe[0] += yr.x*tw.x + yi.x*tw.y;
            accRe[1] += yr.y*tw.x + yi.y*tw.y;
            accRe[2] += yr.z*tw.x + yi.z*tw.y;
            accRe[3] += yr.w*tw.x + yi.w*tw.y;
            accIm[0] += yi.x*tw.x - yr.x*tw.y;
            accIm[1] += yi.y*tw.x - yr.y*tw.y;
            accIm[2] += yi.z*tw.x - yr.z*tw.y;
            accIm[3] += yi.w*tw.x - yr.w*tw.y;
        }
    }
    long long base = ((long long)((b*32 + kxi)*16 + ky))*64 + chalf*32 + 4*cq;
    *(float4*)&ws[OFF_FTRE + base] = make_float4(accRe[0], accRe[1], accRe[2], accRe[3]);
    *(float4*)&ws[OFF_FTIM + base] = make_float4(accIm[0], accIm[1], accIm[2], accIm[3]);
}

// ---- mode mix (unchanged) ----
__global__ __launch_bounds__(256) void k_mix(float* ws, int l) {
    __shared__ __align__(16) float2 s_ft[CB*64];
    int t = threadIdx.x;
    int kk = blockIdx.x;
    int kxi = kk >> 4, ky = kk & 15;
    for (int j = 0; j < 2; j++) {
        int idx = j*256 + t;
        int i = idx & 63, b = idx >> 6;
        long long a = ((long long)(b*32 + kxi)*16 + ky)*64 + i;
        s_ft[b*64 + i] = make_float2(ws[OFF_FTRE + a], ws[OFF_FTIM + a]);
    }
    __syncthreads();
    int o = t & 63, bq = t >> 6;
    const float* wr = ws + OFF_WTRE + (((long long)l*32 + kxi)*16 + ky)*4096;
    const float* wi = ws + OFF_WTIM + (((long long)l*32 + kxi)*16 + ky)*4096;
    float accRe[2] = {0.f,0.f}, accIm[2] = {0.f,0.f};
    #pragma unroll 4
    for (int i = 0; i < 64; i++) {
        float wrv = wr[i*64 + o], wiv = wi[i*64 + o];
        #pragma unroll
        for (int j = 0; j < 2; j++) {
            float2 a = s_ft[(bq*2 + j)*64 + i];
            accRe[j] += a.x*wrv - a.y*wiv;
            accIm[j] += a.x*wiv + a.y*wrv;
        }
    }
    #pragma unroll
    for (int j = 0; j < 2; j++) {
        int b = bq*2 + j;
        long long a = ((long long)(b*32 + kxi)*16 + ky)*64 + o;
        ws[OFF_ORE + a] = accRe[j];
        ws[OFF_OIM + a] = accIm[j];
    }
}

// ---- IDFT along H (unchanged) ----
__global__ __launch_bounds__(256) void k_idfth(float* ws) {
    __shared__ __align__(16) float2 s_o[32*64];
    __shared__ __align__(16) float s_tw[512];
    int t = threadIdx.x;
    int bk = blockIdx.x;
    int hh2 = bk & 1;
    int ky = (bk >> 1) & 15;
    int b = bk >> 5;
    ((float2*)s_tw)[t] = ((const float2*)(ws + OFF_TW))[t];
    for (int j = 0; j < 8; j++) {
        int idx = j*256 + t;
        int o = idx & 63, kxi = idx >> 6;
        long long a = ((long long)(b*32 + kxi)*16 + ky)*64 + o;
        s_o[idx] = make_float2(ws[OFF_ORE + a], ws[OFF_OIM + a]);
    }
    __syncthreads();
    int o = t & 63, hq = t >> 6;
    float orr[32], oii[32];
    #pragma unroll
    for (int k = 0; k < 32; k++) { float2 v = s_o[k*64 + o]; orr[k] = v.x; oii[k] = v.y; }
    float scale = (ky == 0 ? 1.0f : 2.0f) * (1.0f/65536.0f);
    float2* g2 = (float2*)(ws + OFF_G2);
    for (int j = 0; j < 32; j++) {
        int h = hh2*128 + j*4 + hq;
        float gr = 0.f, gi = 0.f;
        #pragma unroll
        for (int k = 0; k < 32; k++) {
            int kxa = (k < 16) ? k : (224 + k);
            float2 tw = ((const float2*)s_tw)[(kxa*h) & 255];
            gr += orr[k]*tw.x - oii[k]*tw.y;
            gi += orr[k]*tw.y + oii[k]*tw.x;
        }
        long long a = (((long long)b*256 + h)*16 + ky)*64 + o;
        g2[a] = make_float2(gr*scale, gi*scale);
    }
}

// ---- fused layer output via MFMA split-bf16 (as round 4, bf16-plane I/O) ----
__global__ __launch_bounds__(256) void k_layer_out(float* ws, const float* cb, int l) {
    __shared__ ushort sAhi[128*64];
    __shared__ ushort sAlo[128*64];
    __shared__ ushort sBhi[64*104];
    __shared__ ushort sBlo[64*104];
    int t = threadIdx.x;
    int bh = blockIdx.x;
    int lane = t & 63, wid = t >> 6;
    int oc = lane & 15, g = lane >> 4;
    ushort* hH = (ushort*)ws;
    ushort* hL = (ushort*)(ws + OFF_HLO_F);

    // B: g part (k=0..31), split fp32 -> hi/lo
    const float2* g2 = (const float2*)(ws + OFF_G2) + (long long)bh*1024;
    for (int n = t; n < 1024; n += 256) {
        int ky = n >> 6, o = n & 63;
        float2 gv = g2[n];
        ushort h0,l0,h1,l1; split2(gv.x,h0,l0); split2(gv.y,h1,l1);
        int idx = o*104 + 2*ky;
        sBhi[idx] = h0; sBhi[idx+1] = h1;
        sBlo[idx] = l0; sBlo[idx+1] = l1;
    }
    // B: cw part (k=32..95), straight copy
    {
        const ushort* ch = (const ushort*)(ws + OFF_CWB) + (long long)l*4096;
        const ushort* clo = (const ushort*)(ws + OFF_CWB) + 16384 + (long long)l*4096;
        for (int n = t; n < 512; n += 256) {
            int o = n >> 3, i0 = (n & 7)*8;
            *(uint4*)&sBhi[o*104 + 32 + i0] = *(const uint4*)&ch[o*64 + i0];
            *(uint4*)&sBlo[o*104 + 32 + i0] = *(const uint4*)&clo[o*64 + i0];
        }
    }
    __syncthreads();
    int o = wid*16 + oc;
    bf16x8 B_h[3], B_l[3];
    #pragma unroll
    for (int s = 0; s < 3; s++) {
        int kb = 32*s + 8*g;
        B_h[s] = *(bf16x8*)&sBhi[o*104 + kb];
        B_l[s] = *(bf16x8*)&sBlo[o*104 + kb];
    }
    float cbv = cb[o];
    const ushort* twh = (const ushort*)(ws + OFF_TWA);
    const ushort* twl = twh + 8192;
    long long rowbase = (long long)bh * 16384;

    for (int half = 0; half < 2; half++) {
        const ushort* srcH = hH + rowbase + half*8192;
        const ushort* srcL = hL + rowbase + half*8192;
        for (int n = t; n < 1024; n += 256) {
            int row = n >> 3, i0 = (n & 7)*8;
            int idx = row*64 + (i0 ^ ((row & 7) << 3));
            *(uint4*)&sAhi[idx] = *(const uint4*)&srcH[row*64 + i0];
            *(uint4*)&sAlo[idx] = *(const uint4*)&srcL[row*64 + i0];
        }
        __syncthreads();
        f32x4 acc[8];
        #pragma unroll
        for (int wt = 0; wt < 8; wt++) acc[wt] = (f32x4){0.f,0.f,0.f,0.f};
        #pragma unroll
        for (int wt = 0; wt < 8; wt++) {
            int gwt = half*8 + wt;
            bf16x8 A0h = *(const bf16x8*)&twh[(gwt*64 + lane)*8];
            bf16x8 A0l = *(const bf16x8*)&twl[(gwt*64 + lane)*8];
            int row = wt*16 + oc;
            int base = row*64;
            int sw = (row & 7) << 3;
            bf16x8 A1h = *(bf16x8*)&sAhi[base + ((8*g) ^ sw)];
            bf16x8 A1l = *(bf16x8*)&sAlo[base + ((8*g) ^ sw)];
            bf16x8 A2h = *(bf16x8*)&sAhi[base + ((32 + 8*g) ^ sw)];
            bf16x8 A2l = *(bf16x8*)&sAlo[base + ((32 + 8*g) ^ sw)];
            f32x4 a = acc[wt];
            a = __builtin_amdgcn_mfma_f32_16x16x32_bf16(A0h, B_h[0], a, 0,0,0);
            a = __builtin_amdgcn_mfma_f32_16x16x32_bf16(A0l, B_h[0], a, 0,0,0);
            a = __builtin_amdgcn_mfma_f32_16x16x32_bf16(A0h, B_l[0], a, 0,0,0);
            a = __builtin_amdgcn_mfma_f32_16x16x32_bf16(A1h, B_h[1], a, 0,0,0);
            a = __builtin_amdgcn_mfma_f32_16x16x32_bf16(A1l, B_h[1], a, 0,0,0);
            a = __builtin_amdgcn_mfma_f32_16x16x32_bf16(A1h, B_l[1], a, 0,0,0);
            a = __builtin_amdgcn_mfma_f32_16x16x32_bf16(A2h, B_h[2], a, 0,0,0);
            a = __builtin_amdgcn_mfma_f32_16x16x32_bf16(A2l, B_h[2], a, 0,0,0);
            a = __builtin_amdgcn_mfma_f32_16x16x32_bf16(A2h, B_l[2], a, 0,0,0);
            acc[wt] = a;
        }
        #pragma unroll
        for (int wt = 0; wt < 8; wt++) {
            #pragma unroll
            for (int r = 0; r < 4; r++) {
                float v = acc[wt][r] + cbv;
                float gv = GELU(v);
                ushort hi, lo; split2(gv, hi, lo);
                long long oaddr = rowbase + (long long)(half*128 + wt*16 + 4*g + r)*64 + o;
                hH[oaddr] = hi;
                hL[oaddr] = lo;
            }
        }
        __syncthreads();
    }
}

// ---- projection via MFMA: u[64w x 128] = h@p1t (+b1, gelu) ; out = u@p2 + b2 ----
__global__ __launch_bounds__(256) void k_proj(float* ws, const float* p1b,
                                              const float* p2w, const float* p2b, float* out) {
    __shared__ ushort sAhi[64*64];
    __shared__ ushort sAlo[64*64];
    __shared__ float s_u[64*129];
    __shared__ float s_p2[256];
    int t = threadIdx.x;
    int bh = blockIdx.x;
    int lane = t & 63, wid = t >> 6;
    int oc = lane & 15, g = lane >> 4;
    s_p2[t] = p2w[t];
    const ushort* hH = (const ushort*)ws;
    const ushort* hL = (const ushort*)(ws + OFF_HLO_F);
    const ushort* ph = (const ushort*)(ws + OFF_P1T);
    const ushort* pl = ph + 8192;
    bf16x8 Bh[2][2], Bl[2][2];
    float p1bv[2];
    #pragma unroll
    for (int q = 0; q < 2; q++) {
        int u = (wid*2 + q)*16 + oc;
        p1bv[q] = p1b[u];
        #pragma unroll
        for (int ks = 0; ks < 2; ks++) {
            Bh[q][ks] = *(const bf16x8*)&ph[u*64 + ks*32 + 8*g];
            Bl[q][ks] = *(const bf16x8*)&pl[u*64 + ks*32 + 8*g];
        }
    }
    float p2b0 = p2b[0], p2b1 = p2b[1];
    long long rowbase = (long long)bh * 16384;
    float* obase = out + (long long)bh * 512;
    for (int qt = 0; qt < 4; qt++) {
        __syncthreads();
        for (int r = 0; r < 2; r++) {
            int n = r*256 + t;
            int row = n >> 3, i0 = (n & 7)*8;
            long long gidx = rowbase + (long long)(qt*64 + row)*64 + i0;
            int idx = row*64 + (i0 ^ ((row & 7) << 3));
            *(uint4*)&sAhi[idx] = *(const uint4*)&hH[gidx];
            *(uint4*)&sAlo[idx] = *(const uint4*)&hL[gidx];
        }
        __syncthreads();
        #pragma unroll
        for (int mt = 0; mt < 4; mt++) {
            int row = mt*16 + oc;
            int base = row*64, sw = (row & 7) << 3;
            bf16x8 A0h = *(bf16x8*)&sAhi[base + ((8*g) ^ sw)];
            bf16x8 A0l = *(bf16x8*)&sAlo[base + ((8*g) ^ sw)];
            bf16x8 A1h = *(bf16x8*)&sAhi[base + ((32 + 8*g) ^ sw)];
            bf16x8 A1l = *(bf16x8*)&sAlo[base + ((32 + 8*g) ^ sw)];
            #pragma unroll
            for (int q = 0; q < 2; q++) {
                f32x4 a = {0.f,0.f,0.f,0.f};
                a = __builtin_amdgcn_mfma_f32_16x16x32_bf16(A0h, Bh[q][0], a, 0,0,0);
                a = __builtin_amdgcn_mfma_f32_16x16x32_bf16(A0l, Bh[q][0], a, 0,0,0);
                a = __builtin_amdgcn_mfma_f32_16x16x32_bf16(A0h, Bl[q][0], a, 0,0,0);
                a = __builtin_amdgcn_mfma_f32_16x16x32_bf16(A1h, Bh[q][1], a, 0,0,0);
                a = __builtin_amdgcn_mfma_f32_16x16x32_bf16(A1l, Bh[q][1], a, 0,0,0);
                a = __builtin_amdgcn_mfma_f32_16x16x32_bf16(A1h, Bl[q][1], a, 0,0,0);
                #pragma unroll
                for (int r = 0; r < 4; r++) {
                    float v = a[r] + p1bv[q];
                    s_u[(mt*16 + 4*g + r)*129 + (wid*2 + q)*16 + oc] = GELU(v);
                }
            }
        }
        __syncthreads();
        {
            int wl = t >> 2, co = (t >> 1) & 1, seg = t & 1;
            float s = 0.f;
            #pragma unroll 16
            for (int u = 0; u < 64; u++)
                s += s_u[wl*129 + seg*64 + u] * s_p2[(seg*64 + u)*2 + co];
            s += __shfl_xor(s, 1);
            if (seg == 0)
                obase[(qt*64 + wl)*2 + co] = s + (co ? p2b1 : p2b0);
        }
    }
}

extern "C" void kernel_launch(void* const* d_in, const int* in_sizes, int n_in,
                              void* d_out, int out_size, void* d_ws, size_t ws_size,
                              hipStream_t stream) {
    (void)in_sizes; (void)n_in; (void)out_size; (void)ws_size;
    const float* x   = (const float*)d_in[0];
    const float* lw  = (const float*)d_in[1];
    const float* lb  = (const float*)d_in[2];
    const float* w1r = (const float*)d_in[3];
    const float* w1i = (const float*)d_in[4];
    const float* w2r = (const float*)d_in[5];
    const float* w2i = (const float*)d_in[6];
    const float* cw  = (const float*)d_in[7];
    const float* cb  = (const float*)d_in[8];
    const float* p1w = (const float*)d_in[9];
    const float* p1b = (const float*)d_in[10];
    const float* p2w = (const float*)d_in[11];
    const float* p2b = (const float*)d_in[12];
    float* ws  = (float*)d_ws;
    float* out = (float*)d_out;

    k_init_tables<<<dim3(1), dim3(256), 0, stream>>>(ws);
    k_wtrans<<<dim3(2048), dim3(256), 0, stream>>>(w1r, w1i, w2r, w2i, ws);
    k_cwtrans<<<dim3(64), dim3(256), 0, stream>>>(cw, ws);
    k_p1trans<<<dim3(32), dim3(256), 0, stream>>>(p1w, ws);
    for (int chunk = 0; chunk < 16/CB; chunk++) {
        k_lift<<<dim3(CB*65536/32), dim3(256), 0, stream>>>(x, lw, lb, ws, chunk*CB);
        for (int l = 0; l < 4; l++) {
            k_dftw<<<dim3(CB*256), dim3(256), 0, stream>>>(ws);
            k_dfth<<<dim3(CB*32), dim3(256), 0, stream>>>(ws);
            k_mix<<<dim3(512), dim3(256), 0, stream>>>(ws, l);
            k_idfth<<<dim3(CB*32), dim3(256), 0, stream>>>(ws);
            k_layer_out<<<dim3(CB*256), dim3(256), 0, stream>>>(ws, cb + l*64, l);
        }
        k_proj<<<dim3(CB*256), dim3(256), 0, stream>>>(ws, p1b, p2w, p2b,
                                                       out + (long long)chunk*CB*256*256*2);
    }
}